// Round 11
// baseline (199.691 us; speedup 1.0000x reference)
//
#include <hip/hip_runtime.h>
#include <stdint.h>

typedef short bf16x8 __attribute__((ext_vector_type(8)));
typedef float f32x4  __attribute__((ext_vector_type(4)));
typedef unsigned int u32x4 __attribute__((ext_vector_type(4)));
typedef unsigned int u32x2 __attribute__((ext_vector_type(2)));

// round-half-up bf16 (same max err as RNE, 2 VALU ops)
__device__ __forceinline__ unsigned short f2bf(float f) {
  unsigned int u = __builtin_bit_cast(unsigned int, f) + 0x8000u;
  return (unsigned short)(u >> 16);
}
// pack two f32 -> two bf16 in one dword: 2x v_add + 1x v_perm
__device__ __forceinline__ unsigned int pack2bf(float a, float b) {
  unsigned int ua = __builtin_bit_cast(unsigned int, a) + 0x8000u;
  unsigned int ub = __builtin_bit_cast(unsigned int, b) + 0x8000u;
  return __builtin_amdgcn_perm(ub, ua, 0x07060302);  // [b_hi16 | a_hi16]
}
// HW packed f32->bf16 (RNE), 1 VALU op: lo16 = bf16(a), hi16 = bf16(b)
__device__ __forceinline__ unsigned int cvtpk2bf(float a, float b) {
  unsigned int r;
  asm("v_cvt_pk_bf16_f32 %0, %1, %2" : "=v"(r) : "v"(a), "v"(b));
  return r;
}

// async 16B global->LDS (m97). LDS dest: wave-uniform base + lane*16.
__device__ __forceinline__ void gl2lds16(const void* g, void* l) {
  __builtin_amdgcn_global_load_lds(
      (const __attribute__((address_space(1))) void*)g,
      (__attribute__((address_space(3))) void*)l, 16, 0, 0);
}

// counted vmem wait (T4): N loads may stay in flight
template <int N> __device__ __forceinline__ void wait_vmcnt() {
  asm volatile("s_waitcnt vmcnt(%0)" ::"n"(N) : "memory");
}

// -------- fused prep: cast x (blocks 0..4095) + cast+transpose W (4096..8191) --------
__global__ __launch_bounds__(256) void cast_fused_k(
    const float* __restrict__ x, unsigned short* __restrict__ xb,
    const float* __restrict__ Wq, const float* __restrict__ Wk,
    const float* __restrict__ Wv, const float* __restrict__ Wo,
    unsigned short* __restrict__ Tq, unsigned short* __restrict__ Tk,
    unsigned short* __restrict__ Tv, unsigned short* __restrict__ To) {
  __shared__ float tile[32][33];
  const int tid = threadIdx.x;
  const int bid = blockIdx.x;
  if (bid < 4096) {                 // ---- cast x: fp32 -> bf16, 4 elems/thread
    int i = bid * 256 + tid;
    float4 v = ((const float4*)x)[i];
    u32x2 o;
    o.x = pack2bf(v.x, v.y);
    o.y = pack2bf(v.z, v.w);
    ((u32x2*)xb)[i] = o;
  } else {                          // ---- W: fp32 [K][N] -> bf16 [N][K]
    const int bb = bid - 4096;
    const int z = bb >> 10, rem = bb & 1023;
    const float* W = (z == 0) ? Wq : (z == 1) ? Wk : (z == 2) ? Wv : Wo;
    unsigned short* T = (z == 0) ? Tq : (z == 1) ? Tk : (z == 2) ? Tv : To;
    const int tx = tid & 31, ty = tid >> 5;
    const int n0 = (rem & 31) * 32, k0 = (rem >> 5) * 32;
#pragma unroll
    for (int j = 0; j < 32; j += 8)
      tile[ty + j][tx] = W[(size_t)(k0 + ty + j) * 1024 + n0 + tx];
    __syncthreads();
#pragma unroll
    for (int j = 0; j < 32; j += 8)
      T[(size_t)(n0 + ty + j) * 1024 + k0 + tx] = f2bf(tile[tx][ty + j]);
  }
}

// ---------------- QKV GEMM: 256x256 fine-phase (T3+T4 port) ----------------
// C = A(4096x1024) x B^T(3072x1024), 8 waves 2Mx4N, wave out 128x64,
// acc[8][4]. LDS 128 KB: 2 dbuf x {A 256x64, B 256x64} bf16, each split
// into K-halves (256 rows x 32 K = 16 KB, 2 gl2lds16/thread).
// Per K-sub phase (2 per K-tile of 64, 32 total):
//   wait vmcnt(4)  -- ONLY the halves needed now; next 2 halves stay in
//                     flight (never vmcnt(0) in the loop)
//   s_barrier      -- publishes siblings' staging of those halves
//   stage same-ks halves of tile t+1 into alt dbuf (last read at t-1,
//                     >=2 barriers back -- proven-safe separation)
//   ds_read bfr[4] (kept in regs) + af[4]; 16 MFMA; af2[4]; 16 MFMA
// Uniform loop: t=15 re-stages tile 0 into the dead buffer (keeps vmcnt
// invariant; data never read; no OOB). Grid (12,16)=192 blocks (1/CU).
// Epilogue: Q,K bf16 [bh][s][d] (Q pre-scaled 0.125*log2e); V^T bf16
// [bh][d][s] per-64-tile permuted, group g=((mrep&3)<<2)|quad.
__global__ __launch_bounds__(512, 2) void gemm_qkv8_k(const unsigned short* __restrict__ A,
                                                      const unsigned short* __restrict__ B,
                                                      unsigned short* __restrict__ Cq) {
  constexpr int K = 1024;
  __shared__ alignas(16) short lA[2][2][1024 * 8];   // [buf][ksub][256r x 32k]
  __shared__ alignas(16) short lB[2][2][1024 * 8];
  const int tid = threadIdx.x;
  const int wid = tid >> 6, lane = tid & 63;
  const int l15 = lane & 15, quad = lane >> 4;
  const int waveM = wid >> 2, waveN = wid & 3;       // 2M x 4N
  const int bm = blockIdx.y * 256, bn = blockIdx.x * 256;

  f32x4 acc[8][4];
#pragma unroll
  for (int m = 0; m < 8; ++m)
#pragma unroll
    for (int n = 0; n < 4; ++n) acc[m][n] = (f32x4){0.f, 0.f, 0.f, 0.f};

  // stage one K-half (1024 slots of 16B): slot c holds X[row][kk + ch*8]
  // with row=((c>>6)<<4)|(c&15), ch=(c>>4)&3 (session-proven conflict-free
  // pairing with the R*64+lane fragment read below)
  auto stageHalf = [&](const unsigned short* X, int xoff, int kk, short* dst) {
#pragma unroll
    for (int j = 0; j < 2; ++j) {
      int c = tid + 512 * j;
      int row = ((c >> 6) << 4) | (c & 15);
      int ch = (c >> 4) & 3;
      gl2lds16(X + (size_t)(xoff + row) * K + kk + ch * 8, &dst[(c & ~63) * 8]);
    }
  };

  // prologue: all 4 halves of K-tile 0 into dbuf 0 (8 loads outstanding)
  stageHalf(A, bm, 0, lA[0][0]);
  stageHalf(B, bn, 0, lB[0][0]);
  stageHalf(A, bm, 32, lA[0][1]);
  stageHalf(B, bn, 32, lB[0][1]);

#pragma unroll 1
  for (int t = 0; t < 16; ++t) {
    const int buf = t & 1, nb = buf ^ 1;
    const int nk = ((t + 1) & 15) * 64;              // t=15: dummy re-stage of tile 0
#pragma unroll
    for (int ks = 0; ks < 2; ++ks) {
      wait_vmcnt<4>();                   // this ks's halves landed; other 2 in flight
      __builtin_amdgcn_sched_barrier(0);
      __builtin_amdgcn_s_barrier();      // siblings' staging of these halves visible
      __builtin_amdgcn_sched_barrier(0);
      stageHalf(A, bm, nk + ks * 32, &lA[nb][ks][0]);   // 2 loads
      stageHalf(B, bn, nk + ks * 32, &lB[nb][ks][0]);   // 2 loads -> back to 8
      const short* la = &lA[buf][ks][0];
      const short* lb = &lB[buf][ks][0];
      bf16x8 bfr[4], af[4], af2[4];
#pragma unroll
      for (int n = 0; n < 4; ++n)        // B cols waveN*64 + n*16 + l15
        bfr[n] = *(const bf16x8*)&lb[(((waveN * 4 + n) * 64) + lane) * 8];
#pragma unroll
      for (int m = 0; m < 4; ++m)        // A rows waveM*128 + m*16 + l15
        af[m] = *(const bf16x8*)&la[(((waveM * 8 + m) * 64) + lane) * 8];
      __builtin_amdgcn_s_setprio(1);
#pragma unroll
      for (int m = 0; m < 4; ++m)
#pragma unroll
        for (int n = 0; n < 4; ++n)
          acc[m][n] = __builtin_amdgcn_mfma_f32_16x16x32_bf16(af[m], bfr[n], acc[m][n], 0, 0, 0);
      __builtin_amdgcn_s_setprio(0);
#pragma unroll
      for (int m = 0; m < 4; ++m)        // A rows waveM*128 + (4+m)*16 + l15
        af2[m] = *(const bf16x8*)&la[(((waveM * 8 + 4 + m) * 64) + lane) * 8];
      __builtin_amdgcn_s_setprio(1);
#pragma unroll
      for (int m = 0; m < 4; ++m)
#pragma unroll
        for (int n = 0; n < 4; ++n)
          acc[4 + m][n] = __builtin_amdgcn_mfma_f32_16x16x32_bf16(af2[m], bfr[n], acc[4 + m][n], 0, 0, 0);
      __builtin_amdgcn_s_setprio(0);
    }
  }

  // epilogue: C/D layout col = lane&15, row = quad*4 + reg
#pragma unroll
  for (int m = 0; m < 8; ++m)
#pragma unroll
    for (int n = 0; n < 4; ++n) {
      int row = bm + waveM * 128 + m * 16 + quad * 4;    // +r
      int col = bn + waveN * 64 + n * 16 + l15;
      int w = col >> 10, n1 = col & 1023;                // w: 0=Q 1=K 2=V
      int h = n1 >> 6, d = n1 & 63;
      int b = row >> 11, s = row & 2047;
      int bhh = (b << 4) + h;
      if (w == 2) {                                      // V^T permuted [bh][d][s]
        int g = ((m & 3) << 2) | quad;                   // (s&63)>>2
        int ks2 = g >> 3, rem = g & 7;
        int pos = ((ks2 << 2) + (rem & 3)) * 8 + (rem >> 2) * 4;
        u32x2 pk;
        pk.x = pack2bf(acc[m][n][0], acc[m][n][1]);
        pk.y = pack2bf(acc[m][n][2], acc[m][n][3]);
        *(u32x2*)&Cq[(size_t)2 * 4194304 + ((size_t)bhh * 64 + d) * 2048 +
                     (s & ~63) + pos] = pk;
      } else {
        // Q scaled by 1/sqrt(Dh)*log2(e) so flash uses exp2 directly
        float sc = (w == 0) ? 0.18033688011112042f : 1.0f;
#pragma unroll
        for (int r = 0; r < 4; ++r)
          Cq[(size_t)w * 4194304 + ((size_t)bhh * 2048 + s + r) * 64 + d] =
              f2bf(acc[m][n][r] * sc);
      }
    }
}

// --------- out-proj GEMM: depth-2-PAIR pipeline (r10, part of best) ---------
// C = ctx x Wo^T + bias. BM=BN=128, 8 waves 2Mx4N, TN=2, BK=32 chunks
// consumed TWO per barrier round; 4 pair-slots (8 chunk bufs, 128 KB).
// Iter p: stage pair p+2 into slot of pair p-2 -> wait vmcnt(8) ->
// s_barrier -> compute both chunks of pair p.
__global__ __launch_bounds__(512, 2) void gemm_pair_k(const unsigned short* __restrict__ A,
                                                      const unsigned short* __restrict__ B,
                                                      float* __restrict__ C,
                                                      const float* __restrict__ bias,
                                                      int K) {
  constexpr int TN = 2;
  __shared__ alignas(16) short lA[8][512 * 8];
  __shared__ alignas(16) short lB[8][512 * 8];
  const int tid = threadIdx.x;
  const int wid = tid >> 6, lane = tid & 63;
  const int l15 = lane & 15, quad = lane >> 4;
  const int waveM = wid >> 2, waveN = wid & 3;        // 2M x 4N
  const int bm = blockIdx.y * 128, bn = blockIdx.x * 128;

  f32x4 acc[4][TN];
#pragma unroll
  for (int i = 0; i < 4; ++i)
#pragma unroll
    for (int j = 0; j < TN; ++j) acc[i][j] = (f32x4){0.f, 0.f, 0.f, 0.f};

  auto stage = [&](int kk, short* la, short* lb) {
    int c = tid;
    int row = ((c >> 6) << 4) | (c & 15);
    int ch = (c >> 4) & 3;
    gl2lds16(A + (size_t)(bm + row) * K + kk + ch * 8, &la[(c & ~63) * 8]);
    gl2lds16(B + (size_t)(bn + row) * K + kk + ch * 8, &lb[(c & ~63) * 8]);
  };

  auto compute = [&](const short* la, const short* lb) {
    bf16x8 af[4], bfr[TN];
#pragma unroll
    for (int i = 0; i < 4; ++i)
      af[i] = *(const bf16x8*)&la[(((waveM * 4 + i) * 64) + lane) * 8];
#pragma unroll
    for (int j = 0; j < TN; ++j)
      bfr[j] = *(const bf16x8*)&lb[(((waveN * TN + j) * 64) + lane) * 8];
    __builtin_amdgcn_s_setprio(1);
#pragma unroll
    for (int i = 0; i < 4; ++i)
#pragma unroll
      for (int j = 0; j < TN; ++j)
        acc[i][j] = __builtin_amdgcn_mfma_f32_16x16x32_bf16(af[i], bfr[j], acc[i][j], 0, 0, 0);
    __builtin_amdgcn_s_setprio(0);
  };

  const int NP = K >> 6;                  // pair rounds (K=1024 -> 16)
  short *a0 = lA[0], *a1 = lA[1], *a2 = lA[2], *a3 = lA[3],
        *a4 = lA[4], *a5 = lA[5], *a6 = lA[6], *a7 = lA[7];
  short *b0 = lB[0], *b1 = lB[1], *b2 = lB[2], *b3 = lB[3],
        *b4 = lB[4], *b5 = lB[5], *b6 = lB[6], *b7 = lB[7];
  stage(0, a0, b0);  stage(32, a1, b1);   // pair 0
  stage(64, a2, b2); stage(96, a3, b3);   // pair 1
#pragma unroll 1
  for (int p = 0; p < NP - 2; ++p) {
    stage((2 * p + 4) * 32, a4, b4);      // pair p+2 -> slot of pair p-2 (safe)
    stage((2 * p + 5) * 32, a5, b5);
    wait_vmcnt<8>();                      // pair p landed; p+1,p+2 in flight
    __builtin_amdgcn_sched_barrier(0);
    __builtin_amdgcn_s_barrier();
    __builtin_amdgcn_sched_barrier(0);
    compute(a0, b0);
    compute(a1, b1);
    short* t;
    t = a0; a0 = a2; a2 = a4; a4 = a6; a6 = t;
    t = a1; a1 = a3; a3 = a5; a5 = a7; a7 = t;
    t = b0; b0 = b2; b2 = b4; b4 = b6; b6 = t;
    t = b1; b1 = b3; b3 = b5; b5 = b7; b7 = t;
  }
  wait_vmcnt<4>();
  __builtin_amdgcn_sched_barrier(0);
  __builtin_amdgcn_s_barrier();
  __builtin_amdgcn_sched_barrier(0);
  compute(a0, b0);
  compute(a1, b1);
  { short* t;
    t = a0; a0 = a2; a2 = a4; a4 = a6; a6 = t;
    t = a1; a1 = a3; a3 = a5; a5 = a7; a7 = t;
    t = b0; b0 = b2; b2 = b4; b4 = b6; b6 = t;
    t = b1; b1 = b3; b3 = b5; b5 = b7; b7 = t; }
  wait_vmcnt<0>();
  __builtin_amdgcn_sched_barrier(0);
  __builtin_amdgcn_s_barrier();
  __builtin_amdgcn_sched_barrier(0);
  compute(a0, b0);
  compute(a1, b1);

  // epilogue: fp32 + bias
#pragma unroll
  for (int i = 0; i < 4; ++i)
#pragma unroll
    for (int j = 0; j < TN; ++j) {
      int row = bm + waveM * 64 + i * 16 + quad * 4;
      int col = bn + (waveN * TN + j) * 16 + l15;
#pragma unroll
      for (int r = 0; r < 4; ++r)
        C[(size_t)(row + r) * 1024 + col] = acc[i][j][r] + bias[col];
    }
}

// ------------------------- flash attention -------------------------
// r6 version verbatim (measured 45.8 us): K+V LDS-staged, fat 2-tile phase,
// XCD bh-grouping swizzle (K/V L2-resident), cvt_pk P-pack, setprio.
__global__ __launch_bounds__(256, 2) void flash_k(const unsigned short* __restrict__ Qh,
                                                  const unsigned short* __restrict__ Kh,
                                                  const unsigned short* __restrict__ Vt,
                                                  unsigned short* __restrict__ ctxb) {
  constexpr int SL = 2048;
  __shared__ alignas(16) short kt[4][512 * 8];     // [buf][64 keys x 64 d], xor-swizzled
  __shared__ alignas(16) short vt[4][512 * 8];     // [buf][64 d x 64 keys(perm)], swizzled

  const int tid = threadIdx.x;
  const int wid = tid >> 6, lane = tid & 63;
  const int l15 = lane & 15, quad = lane >> 4;
  const int bid = blockIdx.x;
  const int jj = bid >> 3;                          // 0..63
  const int bh = ((bid & 7) << 2) | (jj >> 4);      // 4 bh per XCD
  const int q0 = (jj & 15) * 128 + wid * 32;

  const unsigned short* Qb = Qh + (size_t)bh * SL * 64;
  const unsigned short* Kb = Kh + (size_t)bh * SL * 64;
  const unsigned short* Vb = Vt + (size_t)bh * 64 * SL;   // [d][s-permuted]

  bf16x8 qf[2][2];   // B-frag [n=q=l15][k=d]; Q pre-scaled 0.125*log2e
#pragma unroll
  for (int s = 0; s < 2; ++s)
#pragma unroll
    for (int ks = 0; ks < 2; ++ks)
      qf[s][ks] = *(const bf16x8*)(Qb + (size_t)(q0 + s * 16 + l15) * 64 + ks * 32 + quad * 8);

  f32x4 o[2][4];     // O^T: d = t*16+quad*4+r, q = l15 (per strip)
  f32x4 rs4[2] = {(f32x4){0.f, 0.f, 0.f, 0.f}, (f32x4){0.f, 0.f, 0.f, 0.f}};
  const f32x4 z4 = (f32x4){0.f, 0.f, 0.f, 0.f};
#pragma unroll
  for (int s = 0; s < 2; ++s)
#pragma unroll
    for (int t = 0; t < 4; ++t) o[s][t] = z4;

  // stage one 64-key tile: K 8 KB + V 8 KB over 256 threads -> 4 loads/thread
  auto stage = [&](int kb, short* ktb, short* vtb) {
#pragma unroll
    for (int j2 = 0; j2 < 2; ++j2) {
      int cc = tid + 256 * j2;
      int row = cc >> 3;
      int ko = (cc & 7) ^ (row & 7);
      gl2lds16(Kb + (size_t)(kb + row) * 64 + ko * 8, &ktb[(cc & ~63) * 8]);
      gl2lds16(Vb + (size_t)row * SL + kb + ko * 8, &vtb[(cc & ~63) * 8]);
    }
  };

  // S^T = K Q^T : C tile t: row=key=t*16+quad*4+r, col=q=l15
  auto computeQK = [&](const short* ktb, f32x4 (&sv)[2][4]) {
    __builtin_amdgcn_s_setprio(1);
#pragma unroll
    for (int t = 0; t < 4; ++t) {
      int key = t * 16 + l15;
      bf16x8 kf0 = *(bf16x8*)&ktb[(key * 8 + (quad ^ (key & 7))) * 8];
      bf16x8 kf1 = *(bf16x8*)&ktb[(key * 8 + ((4 + quad) ^ (key & 7))) * 8];
#pragma unroll
      for (int s = 0; s < 2; ++s) {
        sv[s][t] = __builtin_amdgcn_mfma_f32_16x16x32_bf16(kf0, qf[s][0], z4, 0, 0, 0);
        sv[s][t] = __builtin_amdgcn_mfma_f32_16x16x32_bf16(kf1, qf[s][1], sv[s][t], 0, 0, 0);
      }
    }
    __builtin_amdgcn_s_setprio(0);
  };

  // p = exp2(s); l partials; pack P (cvt_pk); O^T += V^T · P
  auto computeSMPV = [&](const short* vtb, f32x4 (&sv)[2][4]) {
    u32x4 pf[2][2];
#pragma unroll
    for (int s = 0; s < 2; ++s)
#pragma unroll
      for (int t = 0; t < 4; ++t) {
        f32x4 p;
#pragma unroll
        for (int r = 0; r < 4; ++r) p[r] = __builtin_amdgcn_exp2f(sv[s][t][r]);
        rs4[s] += p;
        pf[s][t >> 1][(t & 1) * 2 + 0] = cvtpk2bf(p[0], p[1]);
        pf[s][t >> 1][(t & 1) * 2 + 1] = cvtpk2bf(p[2], p[3]);
      }
    __builtin_amdgcn_s_setprio(1);
#pragma unroll
    for (int t = 0; t < 4; ++t) {
      int d = t * 16 + l15;
#pragma unroll
      for (int ks = 0; ks < 2; ++ks) {
        bf16x8 vf = *(bf16x8*)&vtb[(d * 8 + ((ks * 4 + quad) ^ (d & 7))) * 8];
#pragma unroll
        for (int s = 0; s < 2; ++s)
          o[s][t] = __builtin_amdgcn_mfma_f32_16x16x32_bf16(
              vf, __builtin_bit_cast(bf16x8, pf[s][ks]), o[s][t], 0, 0, 0);
      }
    }
    __builtin_amdgcn_s_setprio(0);
  };

  short *kA0 = kt[0], *kA1 = kt[1], *kB0 = kt[2], *kB1 = kt[3];
  short *vA0 = vt[0], *vA1 = vt[1], *vB0 = vt[2], *vB1 = vt[3];
  stage(0, kA0, vA0);
  stage(64, kA1, vA1);
#pragma unroll 1
  for (int i2 = 0; i2 < 16; ++i2) {
    wait_vmcnt<0>();                       // pair A (tiles 2i2,2i2+1) landed
    __builtin_amdgcn_sched_barrier(0);
    __builtin_amdgcn_s_barrier();          // all waves' staging visible; pair B free
    __builtin_amdgcn_sched_barrier(0);
    if (i2 < 15) {                         // stage next pair into B (post-barrier)
      stage((2 * i2 + 2) * 64, kB0, vB0);
      stage((2 * i2 + 3) * 64, kB1, vB1);
    }
    f32x4 sv0[2][4], sv1[2][4];
    computeQK(kA0, sv0);
    computeQK(kA1, sv1);                   // independent of SM(t0): pipes overlap
    computeSMPV(vA0, sv0);
    computeSMPV(vA1, sv1);
    short* t;
    t = kA0; kA0 = kB0; kB0 = t;  t = kA1; kA1 = kB1; kB1 = t;
    t = vA0; vA0 = vB0; vB0 = t;  t = vA1; vA1 = vB1; vB1 = t;
  }

  // final l reduction across quads (same q=l15 on lanes l15+16k) + store
  const int bb = bh >> 4, h = bh & 15;
#pragma unroll
  for (int s = 0; s < 2; ++s) {
    float v = (rs4[s][0] + rs4[s][1]) + (rs4[s][2] + rs4[s][3]);
    v += __shfl_xor(v, 16);
    v += __shfl_xor(v, 32);
    float inv = 1.0f / v;
    int tok = q0 + s * 16 + l15;
    size_t base = ((size_t)(bb * 2048 + tok)) * 1024 + h * 64;
#pragma unroll
    for (int t = 0; t < 4; ++t) {
      u32x2 pk;
      pk.x = pack2bf(o[s][t][0] * inv, o[s][t][1] * inv);
      pk.y = pack2bf(o[s][t][2] * inv, o[s][t][3] * inv);
      *(u32x2*)&ctxb[base + t * 16 + quad * 4] = pk;
    }
  }
}

// ------------------------------ launch ------------------------------
extern "C" void kernel_launch(void* const* d_in, const int* in_sizes, int n_in,
                              void* d_out, int out_size, void* d_ws, size_t ws_size,
                              hipStream_t stream) {
  const float* x  = (const float*)d_in[0];
  const float* Wk = (const float*)d_in[1];   // input order: Wk before Wq
  const float* Wq = (const float*)d_in[2];
  const float* Wv = (const float*)d_in[3];
  const float* Wo = (const float*)d_in[4];
  const float* bo = (const float*)d_in[5];
  float* out = (float*)d_out;

  char* ws = (char*)d_ws;
  const size_t MB = 1u << 20;
  unsigned short* xb   = (unsigned short*)(ws);            // 8 MB, reused as ctxb
  unsigned short* WqT  = (unsigned short*)(ws + 8  * MB);  // [3072][1024] packed QKV^T
  unsigned short* WkT  = (unsigned short*)(ws + 10 * MB);
  unsigned short* WvT  = (unsigned short*)(ws + 12 * MB);
  unsigned short* WoT  = (unsigned short*)(ws + 14 * MB);
  unsigned short* Qh   = (unsigned short*)(ws + 16 * MB);  // Q,K [bh][s][d]; V^T perm [bh][d][s]
  unsigned short* ctxb = xb;

  cast_fused_k<<<8192, 256, 0, stream>>>(x, xb, Wq, Wk, Wv, Wo, WqT, WkT, WvT, WoT);
  gemm_qkv8_k<<<dim3(12, 16), 512, 0, stream>>>(xb, WqT, Qh);
  flash_k<<<512, 256, 0, stream>>>(Qh, Qh + 4194304, Qh + 2 * 4194304, ctxb);
  gemm_pair_k<<<dim3(8, 32), 512, 0, stream>>>(ctxb, WoT, out, bo, 1024);
}

// Round 12
// 183.964 us; speedup vs baseline: 1.0855x; 1.0855x over previous
//
#include <hip/hip_runtime.h>
#include <stdint.h>

typedef short bf16x8 __attribute__((ext_vector_type(8)));
typedef float f32x4  __attribute__((ext_vector_type(4)));
typedef unsigned int u32x4 __attribute__((ext_vector_type(4)));
typedef unsigned int u32x2 __attribute__((ext_vector_type(2)));

// round-half-up bf16 (same max err as RNE, 2 VALU ops)
__device__ __forceinline__ unsigned short f2bf(float f) {
  unsigned int u = __builtin_bit_cast(unsigned int, f) + 0x8000u;
  return (unsigned short)(u >> 16);
}
// pack two f32 -> two bf16 in one dword: 2x v_add + 1x v_perm
__device__ __forceinline__ unsigned int pack2bf(float a, float b) {
  unsigned int ua = __builtin_bit_cast(unsigned int, a) + 0x8000u;
  unsigned int ub = __builtin_bit_cast(unsigned int, b) + 0x8000u;
  return __builtin_amdgcn_perm(ub, ua, 0x07060302);  // [b_hi16 | a_hi16]
}
// HW packed f32->bf16 (RNE), 1 VALU op: lo16 = bf16(a), hi16 = bf16(b)
__device__ __forceinline__ unsigned int cvtpk2bf(float a, float b) {
  unsigned int r;
  asm("v_cvt_pk_bf16_f32 %0, %1, %2" : "=v"(r) : "v"(a), "v"(b));
  return r;
}

// async 16B global->LDS (m97). LDS dest: wave-uniform base + lane*16.
__device__ __forceinline__ void gl2lds16(const void* g, void* l) {
  __builtin_amdgcn_global_load_lds(
      (const __attribute__((address_space(1))) void*)g,
      (__attribute__((address_space(3))) void*)l, 16, 0, 0);
}

// counted vmem wait (T4): N loads may stay in flight
template <int N> __device__ __forceinline__ void wait_vmcnt() {
  asm volatile("s_waitcnt vmcnt(%0)" ::"n"(N) : "memory");
}

// -------- fused prep: cast x (blocks 0..4095) + cast+transpose W (4096..8191) --------
__global__ __launch_bounds__(256) void cast_fused_k(
    const float* __restrict__ x, unsigned short* __restrict__ xb,
    const float* __restrict__ Wq, const float* __restrict__ Wk,
    const float* __restrict__ Wv, const float* __restrict__ Wo,
    unsigned short* __restrict__ Tq, unsigned short* __restrict__ Tk,
    unsigned short* __restrict__ Tv, unsigned short* __restrict__ To) {
  __shared__ float tile[32][33];
  const int tid = threadIdx.x;
  const int bid = blockIdx.x;
  if (bid < 4096) {                 // ---- cast x: fp32 -> bf16, 4 elems/thread
    int i = bid * 256 + tid;
    float4 v = ((const float4*)x)[i];
    u32x2 o;
    o.x = pack2bf(v.x, v.y);
    o.y = pack2bf(v.z, v.w);
    ((u32x2*)xb)[i] = o;
  } else {                          // ---- W: fp32 [K][N] -> bf16 [N][K]
    const int bb = bid - 4096;
    const int z = bb >> 10, rem = bb & 1023;
    const float* W = (z == 0) ? Wq : (z == 1) ? Wk : (z == 2) ? Wv : Wo;
    unsigned short* T = (z == 0) ? Tq : (z == 1) ? Tk : (z == 2) ? Tv : To;
    const int tx = tid & 31, ty = tid >> 5;
    const int n0 = (rem & 31) * 32, k0 = (rem >> 5) * 32;
#pragma unroll
    for (int j = 0; j < 32; j += 8)
      tile[ty + j][tx] = W[(size_t)(k0 + ty + j) * 1024 + n0 + tx];
    __syncthreads();
#pragma unroll
    for (int j = 0; j < 32; j += 8)
      T[(size_t)(n0 + ty + j) * 1024 + k0 + tx] = f2bf(tile[tx][ty + j]);
  }
}

// ------------- GEMM C = A * B^T (A:[M][K] bf16, B:[N][K] bf16) -------------
// r6 config (session-best QKV: 46.8-47.6 us). BM=128, BN=WN*TN*16, BK=32.
// 4-buffer depth-3 pipeline, HOISTED stage + double-flight counted vmcnt:
//   iter t: stage(t+2) [buf held tile t-2; iter t-1's barrier protects] ->
//   wait vmcnt(2*PT) [tile t landed; t+1,t+2 in flight] -> s_barrier ->
//   compute(t). T5 setprio around the MFMA cluster.
// MODE 0 <0,6,4,512>: QKV 128x384, 8 waves 2Mx4N, 128 KB LDS, grid 8x32=256
//   = 1 block/CU, zero tail; xcd=bx -> each XCD owns one 768 KB B-slab
//   (L2-resident; dispatch round-robin makes XCD = bx for this grid).
// Epilogue: Q,K bf16 [bh][s][d] (Q pre-scaled 0.125*log2e); V^T bf16
// [bh][d][s] per-64-tile permuted (flash P order).
// Session ledger (do not revisit): depth-1/vmcnt(0) variants 55.9-82 us;
// 256x256 fine-phase port 59.5 us (grid 192 = 75% coverage + no intra-phase
// interleave); TN=4/2-blocks 51.2; K-in-regs n/a here.
template <int MODE, int TN, int WN, int NTHR>
__global__ __launch_bounds__(NTHR, 2) void gemm_bt_k(const unsigned short* __restrict__ A,
                                                     const unsigned short* __restrict__ B,
                                                     void* __restrict__ C,
                                                     const float* __restrict__ bias,
                                                     int K) {
  constexpr int BN = WN * TN * 16;
  constexpr int ALD = 512 / NTHR;        // A 16B-loads per thread per tile
  constexpr int BLD = BN * 4 / NTHR;     // B 16B-loads per thread per tile
  constexpr int PT = ALD + BLD;
  __shared__ alignas(16) short lA[4][512 * 8];        // 128 x 32 bf16 per buf
  __shared__ alignas(16) short lB[4][BN * 4 * 8];     // BN x 32 bf16 per buf
  const int tid = threadIdx.x;
  const int wid = tid >> 6, lane = tid & 63;
  const int l15 = lane & 15, quad = lane >> 4;
  const int waveM = wid / WN, waveN = wid % WN;
  const int bm = blockIdx.y * 128, bn = blockIdx.x * BN;

  f32x4 acc[4][TN];
#pragma unroll
  for (int i = 0; i < 4; ++i)
#pragma unroll
    for (int j = 0; j < TN; ++j) acc[i][j] = (f32x4){0.f, 0.f, 0.f, 0.f};

  // LDS slot c (16B) holds X[row=((c>>6)<<4)|(c&15)][8 elems at col ((c>>4)&3)*8]
  auto stage = [&](int kk, short* la, short* lb) {
#pragma unroll
    for (int j = 0; j < ALD; ++j) {
      int c = tid + NTHR * j;
      int row = ((c >> 6) << 4) | (c & 15);
      int ch = (c >> 4) & 3;
      gl2lds16(A + (size_t)(bm + row) * K + kk + ch * 8, &la[(c & ~63) * 8]);
    }
#pragma unroll
    for (int j = 0; j < BLD; ++j) {
      int c = tid + NTHR * j;
      int row = ((c >> 6) << 4) | (c & 15);
      int ch = (c >> 4) & 3;
      gl2lds16(B + (size_t)(bn + row) * K + kk + ch * 8, &lb[(c & ~63) * 8]);
    }
  };

  // read slot (R*64+lane): row = 16R + l15, cols = quad*8..+8  (MFMA A/B frag)
  auto compute = [&](const short* la, const short* lb) {
    bf16x8 af[4], bfr[TN];
#pragma unroll
    for (int i = 0; i < 4; ++i)
      af[i] = *(const bf16x8*)&la[(((waveM * 4 + i) * 64) + lane) * 8];
#pragma unroll
    for (int j = 0; j < TN; ++j)
      bfr[j] = *(const bf16x8*)&lb[(((waveN * TN + j) * 64) + lane) * 8];
    __builtin_amdgcn_s_setprio(1);                    // T5: favor MFMA cluster
#pragma unroll
    for (int i = 0; i < 4; ++i)
#pragma unroll
      for (int j = 0; j < TN; ++j)
        acc[i][j] = __builtin_amdgcn_mfma_f32_16x16x32_bf16(af[i], bfr[j], acc[i][j], 0, 0, 0);
    __builtin_amdgcn_s_setprio(0);
  };

  const int NT = K >> 5;  // K-steps of 32
  short *pa0 = lA[0], *pa1 = lA[1], *pa2 = lA[2], *pa3 = lA[3];
  short *pb0 = lB[0], *pb1 = lB[1], *pb2 = lB[2], *pb3 = lB[3];
  stage(0, pa0, pb0);
  stage(32, pa1, pb1);
#pragma unroll 1
  for (int t = 0; t < NT - 2; ++t) {
    stage((t + 2) * 32, pa2, pb2);         // hoisted: buf held tile t-2 (safe)
    wait_vmcnt<2 * PT>();                  // tile t landed; t+1,t+2 in flight
    __builtin_amdgcn_sched_barrier(0);
    __builtin_amdgcn_s_barrier();          // publish siblings' tile-t staging
    __builtin_amdgcn_sched_barrier(0);
    compute(pa0, pb0);
    short* ta = pa0; pa0 = pa1; pa1 = pa2; pa2 = pa3; pa3 = ta;
    short* tb = pb0; pb0 = pb1; pb1 = pb2; pb2 = pb3; pb3 = tb;
  }
  wait_vmcnt<PT>();
  __builtin_amdgcn_sched_barrier(0);
  __builtin_amdgcn_s_barrier();
  __builtin_amdgcn_sched_barrier(0);
  compute(pa0, pb0);
  { short* ta = pa0; pa0 = pa1; pa1 = pa2; pa2 = pa3; pa3 = ta;
    short* tb = pb0; pb0 = pb1; pb1 = pb2; pb2 = pb3; pb3 = tb; }
  wait_vmcnt<0>();
  __builtin_amdgcn_sched_barrier(0);
  __builtin_amdgcn_s_barrier();
  __builtin_amdgcn_sched_barrier(0);
  compute(pa0, pb0);

  // C/D layout: col = lane&15, row = quad*4 + reg
#pragma unroll
  for (int i = 0; i < 4; ++i)
#pragma unroll
    for (int j = 0; j < TN; ++j) {
      int row = bm + waveM * 64 + i * 16 + quad * 4;     // +r
      int col = bn + (waveN * TN + j) * 16 + l15;
      if (MODE == 0) {
        unsigned short* Cq = (unsigned short*)C;
        int w = col >> 10, n1 = col & 1023;              // w: 0=Q 1=K 2=V
        int h = n1 >> 6, d = n1 & 63;
        int b = row >> 11, s = row & 2047;
        int bhh = (b << 4) + h;
        if (w == 2) {                                    // V^T permuted [bh][d][s]
          int g = (i << 2) + quad;                       // group (s&63)>>2 = 4i+quad
          int ks2 = g >> 3, rem = g & 7;
          int pos = ((ks2 << 2) + (rem & 3)) * 8 + (rem >> 2) * 4;
          u32x2 pk;
          pk.x = pack2bf(acc[i][j][0], acc[i][j][1]);
          pk.y = pack2bf(acc[i][j][2], acc[i][j][3]);
          *(u32x2*)&Cq[(size_t)2 * 4194304 + ((size_t)bhh * 64 + d) * 2048 +
                       (s & ~63) + pos] = pk;
        } else {
          // Q scaled by 1/sqrt(Dh)*log2(e) so flash uses exp2 directly
          float sc = (w == 0) ? 0.18033688011112042f : 1.0f;
#pragma unroll
          for (int r = 0; r < 4; ++r)
            Cq[(size_t)w * 4194304 + ((size_t)bhh * 2048 + s + r) * 64 + d] =
                f2bf(acc[i][j][r] * sc);
        }
      } else {
#pragma unroll
        for (int r = 0; r < 4; ++r)
          ((float*)C)[(size_t)(row + r) * 1024 + col] = acc[i][j][r] + bias[col];
      }
    }
}

// --------- out-proj GEMM: depth-2-PAIR pipeline (r10, part of best) ---------
// C = ctx x Wo^T + bias. BM=BN=128, 8 waves 2Mx4N, TN=2, BK=32 chunks
// consumed TWO per barrier round; 4 pair-slots (8 chunk bufs, 128 KB).
// Iter p: stage pair p+2 into slot of pair p-2 -> wait vmcnt(8) ->
// s_barrier -> compute both chunks of pair p.
__global__ __launch_bounds__(512, 2) void gemm_pair_k(const unsigned short* __restrict__ A,
                                                      const unsigned short* __restrict__ B,
                                                      float* __restrict__ C,
                                                      const float* __restrict__ bias,
                                                      int K) {
  constexpr int TN = 2;
  __shared__ alignas(16) short lA[8][512 * 8];
  __shared__ alignas(16) short lB[8][512 * 8];
  const int tid = threadIdx.x;
  const int wid = tid >> 6, lane = tid & 63;
  const int l15 = lane & 15, quad = lane >> 4;
  const int waveM = wid >> 2, waveN = wid & 3;        // 2M x 4N
  const int bm = blockIdx.y * 128, bn = blockIdx.x * 128;

  f32x4 acc[4][TN];
#pragma unroll
  for (int i = 0; i < 4; ++i)
#pragma unroll
    for (int j = 0; j < TN; ++j) acc[i][j] = (f32x4){0.f, 0.f, 0.f, 0.f};

  auto stage = [&](int kk, short* la, short* lb) {
    int c = tid;
    int row = ((c >> 6) << 4) | (c & 15);
    int ch = (c >> 4) & 3;
    gl2lds16(A + (size_t)(bm + row) * K + kk + ch * 8, &la[(c & ~63) * 8]);
    gl2lds16(B + (size_t)(bn + row) * K + kk + ch * 8, &lb[(c & ~63) * 8]);
  };

  auto compute = [&](const short* la, const short* lb) {
    bf16x8 af[4], bfr[TN];
#pragma unroll
    for (int i = 0; i < 4; ++i)
      af[i] = *(const bf16x8*)&la[(((waveM * 4 + i) * 64) + lane) * 8];
#pragma unroll
    for (int j = 0; j < TN; ++j)
      bfr[j] = *(const bf16x8*)&lb[(((waveN * TN + j) * 64) + lane) * 8];
    __builtin_amdgcn_s_setprio(1);
#pragma unroll
    for (int i = 0; i < 4; ++i)
#pragma unroll
      for (int j = 0; j < TN; ++j)
        acc[i][j] = __builtin_amdgcn_mfma_f32_16x16x32_bf16(af[i], bfr[j], acc[i][j], 0, 0, 0);
    __builtin_amdgcn_s_setprio(0);
  };

  const int NP = K >> 6;                  // pair rounds (K=1024 -> 16)
  short *a0 = lA[0], *a1 = lA[1], *a2 = lA[2], *a3 = lA[3],
        *a4 = lA[4], *a5 = lA[5], *a6 = lA[6], *a7 = lA[7];
  short *b0 = lB[0], *b1 = lB[1], *b2 = lB[2], *b3 = lB[3],
        *b4 = lB[4], *b5 = lB[5], *b6 = lB[6], *b7 = lB[7];
  stage(0, a0, b0);  stage(32, a1, b1);   // pair 0
  stage(64, a2, b2); stage(96, a3, b3);   // pair 1
#pragma unroll 1
  for (int p = 0; p < NP - 2; ++p) {
    stage((2 * p + 4) * 32, a4, b4);      // pair p+2 -> slot of pair p-2 (safe)
    stage((2 * p + 5) * 32, a5, b5);
    wait_vmcnt<8>();                      // pair p landed; p+1,p+2 in flight
    __builtin_amdgcn_sched_barrier(0);
    __builtin_amdgcn_s_barrier();
    __builtin_amdgcn_sched_barrier(0);
    compute(a0, b0);
    compute(a1, b1);
    short* t;
    t = a0; a0 = a2; a2 = a4; a4 = a6; a6 = t;
    t = a1; a1 = a3; a3 = a5; a5 = a7; a7 = t;
    t = b0; b0 = b2; b2 = b4; b4 = b6; b6 = t;
    t = b1; b1 = b3; b3 = b5; b5 = b7; b7 = t;
  }
  wait_vmcnt<4>();
  __builtin_amdgcn_sched_barrier(0);
  __builtin_amdgcn_s_barrier();
  __builtin_amdgcn_sched_barrier(0);
  compute(a0, b0);
  compute(a1, b1);
  { short* t;
    t = a0; a0 = a2; a2 = a4; a4 = a6; a6 = t;
    t = a1; a1 = a3; a3 = a5; a5 = a7; a7 = t;
    t = b0; b0 = b2; b2 = b4; b4 = b6; b6 = t;
    t = b1; b1 = b3; b3 = b5; b5 = b7; b7 = t; }
  wait_vmcnt<0>();
  __builtin_amdgcn_sched_barrier(0);
  __builtin_amdgcn_s_barrier();
  __builtin_amdgcn_sched_barrier(0);
  compute(a0, b0);
  compute(a1, b1);

  // epilogue: fp32 + bias
#pragma unroll
  for (int i = 0; i < 4; ++i)
#pragma unroll
    for (int j = 0; j < TN; ++j) {
      int row = bm + waveM * 64 + i * 16 + quad * 4;
      int col = bn + (waveN * TN + j) * 16 + l15;
#pragma unroll
      for (int r = 0; r < 4; ++r)
        C[(size_t)(row + r) * 1024 + col] = acc[i][j][r] + bias[col];
    }
}

// ------------------------- flash attention -------------------------
// r6 version verbatim (measured 45.8 us): K+V LDS-staged, fat 2-tile phase,
// XCD bh-grouping swizzle (K/V L2-resident: FETCH 12.3 MB), cvt_pk P-pack,
// setprio. Ledger: K-in-registers refuted twice (r7: 71 us, r8: 74 us).
__global__ __launch_bounds__(256, 2) void flash_k(const unsigned short* __restrict__ Qh,
                                                  const unsigned short* __restrict__ Kh,
                                                  const unsigned short* __restrict__ Vt,
                                                  unsigned short* __restrict__ ctxb) {
  constexpr int SL = 2048;
  __shared__ alignas(16) short kt[4][512 * 8];     // [buf][64 keys x 64 d], xor-swizzled
  __shared__ alignas(16) short vt[4][512 * 8];     // [buf][64 d x 64 keys(perm)], swizzled

  const int tid = threadIdx.x;
  const int wid = tid >> 6, lane = tid & 63;
  const int l15 = lane & 15, quad = lane >> 4;
  const int bid = blockIdx.x;
  const int jj = bid >> 3;                          // 0..63
  const int bh = ((bid & 7) << 2) | (jj >> 4);      // 4 bh per XCD
  const int q0 = (jj & 15) * 128 + wid * 32;

  const unsigned short* Qb = Qh + (size_t)bh * SL * 64;
  const unsigned short* Kb = Kh + (size_t)bh * SL * 64;
  const unsigned short* Vb = Vt + (size_t)bh * 64 * SL;   // [d][s-permuted]

  bf16x8 qf[2][2];   // B-frag [n=q=l15][k=d]; Q pre-scaled 0.125*log2e
#pragma unroll
  for (int s = 0; s < 2; ++s)
#pragma unroll
    for (int ks = 0; ks < 2; ++ks)
      qf[s][ks] = *(const bf16x8*)(Qb + (size_t)(q0 + s * 16 + l15) * 64 + ks * 32 + quad * 8);

  f32x4 o[2][4];     // O^T: d = t*16+quad*4+r, q = l15 (per strip)
  f32x4 rs4[2] = {(f32x4){0.f, 0.f, 0.f, 0.f}, (f32x4){0.f, 0.f, 0.f, 0.f}};
  const f32x4 z4 = (f32x4){0.f, 0.f, 0.f, 0.f};
#pragma unroll
  for (int s = 0; s < 2; ++s)
#pragma unroll
    for (int t = 0; t < 4; ++t) o[s][t] = z4;

  // stage one 64-key tile: K 8 KB + V 8 KB over 256 threads -> 4 loads/thread
  auto stage = [&](int kb, short* ktb, short* vtb) {
#pragma unroll
    for (int j2 = 0; j2 < 2; ++j2) {
      int cc = tid + 256 * j2;
      int row = cc >> 3;
      int ko = (cc & 7) ^ (row & 7);
      gl2lds16(Kb + (size_t)(kb + row) * 64 + ko * 8, &ktb[(cc & ~63) * 8]);
      gl2lds16(Vb + (size_t)row * SL + kb + ko * 8, &vtb[(cc & ~63) * 8]);
    }
  };

  // S^T = K Q^T : C tile t: row=key=t*16+quad*4+r, col=q=l15
  auto computeQK = [&](const short* ktb, f32x4 (&sv)[2][4]) {
    __builtin_amdgcn_s_setprio(1);
#pragma unroll
    for (int t = 0; t < 4; ++t) {
      int key = t * 16 + l15;
      bf16x8 kf0 = *(bf16x8*)&ktb[(key * 8 + (quad ^ (key & 7))) * 8];
      bf16x8 kf1 = *(bf16x8*)&ktb[(key * 8 + ((4 + quad) ^ (key & 7))) * 8];
#pragma unroll
      for (int s = 0; s < 2; ++s) {
        sv[s][t] = __builtin_amdgcn_mfma_f32_16x16x32_bf16(kf0, qf[s][0], z4, 0, 0, 0);
        sv[s][t] = __builtin_amdgcn_mfma_f32_16x16x32_bf16(kf1, qf[s][1], sv[s][t], 0, 0, 0);
      }
    }
    __builtin_amdgcn_s_setprio(0);
  };

  // p = exp2(s); l partials; pack P (cvt_pk); O^T += V^T · P
  auto computeSMPV = [&](const short* vtb, f32x4 (&sv)[2][4]) {
    u32x4 pf[2][2];
#pragma unroll
    for (int s = 0; s < 2; ++s)
#pragma unroll
      for (int t = 0; t < 4; ++t) {
        f32x4 p;
#pragma unroll
        for (int r = 0; r < 4; ++r) p[r] = __builtin_amdgcn_exp2f(sv[s][t][r]);
        rs4[s] += p;
        pf[s][t >> 1][(t & 1) * 2 + 0] = cvtpk2bf(p[0], p[1]);
        pf[s][t >> 1][(t & 1) * 2 + 1] = cvtpk2bf(p[2], p[3]);
      }
    __builtin_amdgcn_s_setprio(1);
#pragma unroll
    for (int t = 0; t < 4; ++t) {
      int d = t * 16 + l15;
#pragma unroll
      for (int ks = 0; ks < 2; ++ks) {
        bf16x8 vf = *(bf16x8*)&vtb[(d * 8 + ((ks * 4 + quad) ^ (d & 7))) * 8];
#pragma unroll
        for (int s = 0; s < 2; ++s)
          o[s][t] = __builtin_amdgcn_mfma_f32_16x16x32_bf16(
              vf, __builtin_bit_cast(bf16x8, pf[s][ks]), o[s][t], 0, 0, 0);
      }
    }
    __builtin_amdgcn_s_setprio(0);
  };

  short *kA0 = kt[0], *kA1 = kt[1], *kB0 = kt[2], *kB1 = kt[3];
  short *vA0 = vt[0], *vA1 = vt[1], *vB0 = vt[2], *vB1 = vt[3];
  stage(0, kA0, vA0);
  stage(64, kA1, vA1);
#pragma unroll 1
  for (int i2 = 0; i2 < 16; ++i2) {
    wait_vmcnt<0>();                       // pair A (tiles 2i2,2i2+1) landed
    __builtin_amdgcn_sched_barrier(0);
    __builtin_amdgcn_s_barrier();          // all waves' staging visible; pair B free
    __builtin_amdgcn_sched_barrier(0);
    if (i2 < 15) {                         // stage next pair into B (post-barrier)
      stage((2 * i2 + 2) * 64, kB0, vB0);
      stage((2 * i2 + 3) * 64, kB1, vB1);
    }
    f32x4 sv0[2][4], sv1[2][4];
    computeQK(kA0, sv0);
    computeQK(kA1, sv1);                   // independent of SM(t0): pipes overlap
    computeSMPV(vA0, sv0);
    computeSMPV(vA1, sv1);
    short* t;
    t = kA0; kA0 = kB0; kB0 = t;  t = kA1; kA1 = kB1; kB1 = t;
    t = vA0; vA0 = vB0; vB0 = t;  t = vA1; vA1 = vB1; vB1 = t;
  }

  // final l reduction across quads (same q=l15 on lanes l15+16k) + store
  const int bb = bh >> 4, h = bh & 15;
#pragma unroll
  for (int s = 0; s < 2; ++s) {
    float v = (rs4[s][0] + rs4[s][1]) + (rs4[s][2] + rs4[s][3]);
    v += __shfl_xor(v, 16);
    v += __shfl_xor(v, 32);
    float inv = 1.0f / v;
    int tok = q0 + s * 16 + l15;
    size_t base = ((size_t)(bb * 2048 + tok)) * 1024 + h * 64;
#pragma unroll
    for (int t = 0; t < 4; ++t) {
      u32x2 pk;
      pk.x = pack2bf(o[s][t][0] * inv, o[s][t][1] * inv);
      pk.y = pack2bf(o[s][t][2] * inv, o[s][t][3] * inv);
      *(u32x2*)&ctxb[base + t * 16 + quad * 4] = pk;
    }
  }
}

// ------------------------------ launch ------------------------------
extern "C" void kernel_launch(void* const* d_in, const int* in_sizes, int n_in,
                              void* d_out, int out_size, void* d_ws, size_t ws_size,
                              hipStream_t stream) {
  const float* x  = (const float*)d_in[0];
  const float* Wk = (const float*)d_in[1];   // input order: Wk before Wq
  const float* Wq = (const float*)d_in[2];
  const float* Wv = (const float*)d_in[3];
  const float* Wo = (const float*)d_in[4];
  const float* bo = (const float*)d_in[5];
  float* out = (float*)d_out;

  char* ws = (char*)d_ws;
  const size_t MB = 1u << 20;
  unsigned short* xb   = (unsigned short*)(ws);            // 8 MB, reused as ctxb
  unsigned short* WqT  = (unsigned short*)(ws + 8  * MB);  // [3072][1024] packed QKV^T
  unsigned short* WkT  = (unsigned short*)(ws + 10 * MB);
  unsigned short* WvT  = (unsigned short*)(ws + 12 * MB);
  unsigned short* WoT  = (unsigned short*)(ws + 14 * MB);
  unsigned short* Qh   = (unsigned short*)(ws + 16 * MB);  // Q,K [bh][s][d]; V^T perm [bh][d][s]
  unsigned short* ctxb = xb;

  cast_fused_k<<<8192, 256, 0, stream>>>(x, xb, Wq, Wk, Wv, Wo, WqT, WkT, WvT, WoT);
  gemm_bt_k<0, 6, 4, 512><<<dim3(8, 32), 512, 0, stream>>>(xb, WqT, Qh, nullptr, 1024);
  flash_k<<<512, 256, 0, stream>>>(Qh, Qh + 4194304, Qh + 2 * 4194304, ctxb);
  gemm_pair_k<<<dim3(8, 32), 512, 0, stream>>>(ctxb, WoT, out, bo, 1024);
}